// Round 3
// baseline (61.846 us; speedup 1.0000x reference)
//
#include <hip/hip_runtime.h>

// counts[b,s] = #{t <= s : x[b,t] == x[b,s]}  (inclusive), B=4, S=4096.
// R7: vocab = 32000 < 2^16, so keys/queries are exact in u16. Pack TWO keys
// per dword in LDS; inner compare uses packed 16-bit math:
//   u = qpk ^ a  (per-half zero iff equal)
//   miss += min_u16x2(u, 1)   -> per-half 0 if match else 1
//   matches = compares - misses
// This halves the broadcast ds_read_b128 count (8 keys/read, was 4) AND cuts
// VALU from 16 to 12 instr per 8 keys -- a strict win whether the inner loop
// is LDS-issue- or VALU-bound. Diagonal tile kept on the verified unpacked
// path via a small diag[64] array. 8 waves, grid (qt 0..63, b 0..3) = 256
// blocks, one per CU. Per-wave full-region share = qt int4s exactly (no
// padding/sentinels needed). Miss accumulators max 2*63=126 < 2^16: no
// overflow.

#define SEQ 4096
#define QT  64        // queries per block
#define SL  8         // waves per block
#define NT  (SL * 64) // 512 threads

typedef unsigned short u16x2 __attribute__((ext_vector_type(2)));

static __device__ __forceinline__ u16x2 bc16(unsigned v) {
    return __builtin_bit_cast(u16x2, v);
}

__global__ __launch_bounds__(NT)
void count_kernel(const int* __restrict__ x, float* __restrict__ out) {
    const int qt  = blockIdx.x;          // query tile 0..63
    const int b   = blockIdx.y;          // batch row
    const int tid = threadIdx.x;
    const int q   = tid & 63;            // query lane
    const int g   = tid >> 6;            // wave id 0..7
    const int* __restrict__ row = x + b * SEQ;

    __shared__ int pk[SEQ / 2];          // packed key pairs, 8 KB
    __shared__ int diag[QT];             // diagonal tile keys, unpacked
    __shared__ int partial[SL][QT];      // 2 KB

    const int K = qt << 6;               // full-region key count (mult of 64)

    // stage: pack keys [0, K) two-per-dword; int4 j holds keys [8j, 8j+8)
    const int n_i4 = qt << 3;            // K/8 packed int4s
    for (int j = tid; j < n_i4; j += NT) {
        const int4 g0 = reinterpret_cast<const int4*>(row)[2 * j];
        const int4 g1 = reinterpret_cast<const int4*>(row)[2 * j + 1];
        int4 p;
        p.x = (int)(((unsigned)g0.x) | ((unsigned)g0.y << 16));
        p.y = (int)(((unsigned)g0.z) | ((unsigned)g0.w << 16));
        p.z = (int)(((unsigned)g1.x) | ((unsigned)g1.y << 16));
        p.w = (int)(((unsigned)g1.z) | ((unsigned)g1.w << 16));
        reinterpret_cast<int4*>(pk)[j] = p;
    }
    if (tid < QT) diag[tid] = row[K + tid];
    __syncthreads();

    const int      qval = diag[q];                       // query value
    const unsigned qpk  = ((unsigned)qval) | ((unsigned)qval << 16);
    const u16x2    one  = {1, 1};

    // full region: wave g scans packed int4s [g*qt, (g+1)*qt)
    u16x2 m0 = {0, 0}, m1 = {0, 0};      // per-half miss accumulators
    const int lo = g * qt;
    const int hi = lo + qt;
    #pragma unroll 4
    for (int j = lo; j < hi; ++j) {
        const int4 a = reinterpret_cast<const int4*>(pk)[j];
        m0 += __builtin_elementwise_min(bc16(qpk ^ (unsigned)a.x), one);
        m1 += __builtin_elementwise_min(bc16(qpk ^ (unsigned)a.y), one);
        m0 += __builtin_elementwise_min(bc16(qpk ^ (unsigned)a.z), one);
        m1 += __builtin_elementwise_min(bc16(qpk ^ (unsigned)a.w), one);
    }
    // compares per wave = 8*qt; matches = compares - misses
    int cnt = (qt << 3) - (int)((unsigned)m0.x + (unsigned)m0.y
                             + (unsigned)m1.x + (unsigned)m1.y);

    // diagonal tile: t = K + k, wave g covers k in [g*8, (g+1)*8), t <= s iff k <= q
    #pragma unroll
    for (int jj = 0; jj < 2; ++jj) {
        const int k = (g << 3) + (jj << 2);
        const int4 a = reinterpret_cast<const int4*>(diag)[k >> 2];
        cnt += (int)((k + 0 <= q) & (qval == a.x))
             + (int)((k + 1 <= q) & (qval == a.y))
             + (int)((k + 2 <= q) & (qval == a.z))
             + (int)((k + 3 <= q) & (qval == a.w));
    }

    partial[g][q] = cnt;
    __syncthreads();

    // partial[w][tid]: stride 64 ints between w -> bank = tid%32, conflict-free
    if (tid < QT) {
        int tot = 0;
        #pragma unroll
        for (int w = 0; w < SL; ++w) tot += partial[w][tid];
        out[b * SEQ + (qt << 6) + tid] = (float)tot;
    }
}

extern "C" void kernel_launch(void* const* d_in, const int* in_sizes, int n_in,
                              void* d_out, int out_size, void* d_ws, size_t ws_size,
                              hipStream_t stream) {
    const int* x = (const int*)d_in[0];
    float* out = (float*)d_out;
    const int B = in_sizes[0] / SEQ;   // 4

    count_kernel<<<dim3(SEQ / QT, B), NT, 0, stream>>>(x, out);
}

// Round 4
// 60.072 us; speedup vs baseline: 1.0295x; 1.0295x over previous
//
#include <hip/hip_runtime.h>

// counts[b,s] = #{t <= s : x[b,t] == x[b,s]}  (inclusive), B=4, S=4096.
// R8: revert to the best-measured structure (R6, 59.9 us). R7's packed-u16
// experiment (halved LDS reads + fewer VALU) was dur-neutral (+2 us = noise),
// proving the inner loop is OFF the critical path: the timed region is
// dominated by the harness's 268 MB workspace re-poison fill (39.5 us at 85%
// of HBM peak -- its own roofline) + ~16 us fixed launch/gap overhead. Kernel
// contribution ~3 us. Structure: 8 waves = 2 waves/SIMD for ds_read latency
// overlap, whole prefix staged in LDS once, broadcast ds_read_b128 scan with
// dual accumulators, conflict-free partial reduction.
// Grid (qt 0..63, b 0..3) = 256 blocks, one per CU.

#define SEQ 4096
#define QT  64    // queries per block
#define SL  8     // t-slices = waves per block

__global__ __launch_bounds__(SL * 64)
void count_kernel(const int* __restrict__ x, float* __restrict__ out) {
    const int qt  = blockIdx.x;          // query tile 0..63
    const int b   = blockIdx.y;          // batch row
    const int tid = threadIdx.x;
    const int q   = tid & 63;            // query lane
    const int g   = tid >> 6;            // t-slice / wave id 0..7
    const int* __restrict__ row = x + b * SEQ;

    __shared__ int prefix[SEQ];          // 16 KB max
    __shared__ int partial[SL][QT];      // 2 KB

    // stage the whole prefix [0, (qt+1)*64) once, coalesced int4
    const int end_i4 = (qt + 1) * (QT / 4);   // (qt+1)*16 int4s
    for (int j = tid; j < end_i4; j += SL * 64)
        reinterpret_cast<int4*>(prefix)[j] =
            reinterpret_cast<const int4*>(row)[j];
    __syncthreads();

    const int s    = (qt << 6) + q;
    const int qval = prefix[s];

    // full region: t in [0, qt*64) = qt*16 int4s; wave g scans
    // int4 indices [g*2*qt, (g+1)*2*qt)  -- per = qt*2 is always even
    int c0 = 0, c1 = 0;
    const int per = qt * (16 / SL);      // int4s per wave
    const int lo  = g * per;
    const int hi  = lo + per;
    #pragma unroll 4
    for (int j = lo; j < hi; j += 2) {   // 2 streams for ILP
        const int4 a  = reinterpret_cast<const int4*>(prefix)[j];
        const int4 a2 = reinterpret_cast<const int4*>(prefix)[j + 1];
        c0 += (qval == a.x)  + (qval == a.y)  + (qval == a.z)  + (qval == a.w);
        c1 += (qval == a2.x) + (qval == a2.y) + (qval == a2.z) + (qval == a2.w);
    }

    // diagonal tile: t = qt*64 + k, k in [g*8, (g+1)*8), qualifies iff k <= q
    const int dbase = qt << 4;           // int4 index of diagonal start
    #pragma unroll
    for (int jj = 0; jj < 2; ++jj) {
        const int k = (g << 3) + (jj << 2);     // local element index
        const int4 a = reinterpret_cast<const int4*>(prefix)[dbase + (k >> 2)];
        c0 += (int)((k + 0 <= q) & (qval == a.x))
            + (int)((k + 1 <= q) & (qval == a.y))
            + (int)((k + 2 <= q) & (qval == a.z))
            + (int)((k + 3 <= q) & (qval == a.w));
    }

    partial[g][q] = c0 + c1;
    __syncthreads();

    // partial[w][tid]: stride 64 ints between w -> bank = tid%32, conflict-free
    if (tid < QT) {
        int tot = 0;
        #pragma unroll
        for (int w = 0; w < SL; ++w) tot += partial[w][tid];
        out[b * SEQ + (qt << 6) + tid] = (float)tot;
    }
}

extern "C" void kernel_launch(void* const* d_in, const int* in_sizes, int n_in,
                              void* d_out, int out_size, void* d_ws, size_t ws_size,
                              hipStream_t stream) {
    const int* x = (const int*)d_in[0];
    float* out = (float*)d_out;
    const int B = in_sizes[0] / SEQ;   // 4

    count_kernel<<<dim3(SEQ / QT, B), SL * 64, 0, stream>>>(x, out);
}